// Round 1
// baseline (677.198 us; speedup 1.0000x reference)
//
#include <hip/hip_runtime.h>
#include <hip/hip_bf16.h>
#include <math.h>

#define GK 75264      // per-frame feature dim (64*1176)
#define NF 256        // frames
#define KC 60         // clusters
#define NSEL 30       // selected spatial centroids
#define NCH 196       // gram split-K channels (K=384 each, 12 steps of 32)
#define KM_IT 10

typedef __attribute__((ext_vector_type(8))) short bf16x8;
typedef __attribute__((ext_vector_type(4))) float f32x4;
typedef __attribute__((ext_vector_type(8))) unsigned short u16x8;

__device__ __forceinline__ float b2f(unsigned short u) {
  union { unsigned u32; float f; } c; c.u32 = ((unsigned)u) << 16; return c.f;
}

// ---------------- Stage A: temporal 2x2 pooling -> bf16 split (H, M) --------
__global__ void pool_kernel(const float* __restrict__ x,
                            __hip_bfloat16* __restrict__ H,
                            __hip_bfloat16* __restrict__ M) {
  unsigned id = blockIdx.x * 256u + threadIdx.x;   // exactly 19,267,584 threads
  unsigned m = id / 1176u, o = id - m * 1176u;
  unsigned t = m >> 6, r = m & 63u;
  unsigned ih = r >> 4, iw = (r >> 2) & 3u, s = r & 3u;
  unsigned i8 = ih * 2u + (s >> 1), j8 = iw * 2u + (s & 1u);
  unsigned c = o / 392u, o2 = o - c * 392u;
  unsigned d = o2 / 196u, o3 = o2 - d * 196u;
  unsigned e = o3 / 14u, f = o3 - e * 14u;
  unsigned a = (e >= 7u) ? 1u : 0u, b = (f >= 7u) ? 1u : 0u;
  unsigned ee = 2u * e - 14u * a, ff = 2u * f - 14u * b;
  unsigned xrow = ((t * 8u + i8) * 8u + j8) * 4u + a * 2u + b;
  unsigned xcol = ((c * 2u + d) * 14u + ee) * 14u + ff;
  const float* base = x + (size_t)xrow * 1176u + xcol;
  float v = 0.25f * ((base[0] + base[1]) + (base[14] + base[15]));
  __hip_bfloat16 hb = __float2bfloat16(v);
  float hf = __bfloat162float(hb);
  __hip_bfloat16 mb = __float2bfloat16(v - hf);
  H[id] = hb;
  M[id] = mb;
}

// ---------------- Stage B1: Gram via bf16 MFMA, 3-product split-float -------
// G = H.H^T + H.M^T + M.H^T  (exact to ~2^-18 relative; mm term negligible).
__global__ __launch_bounds__(512) void gram_mfma(const unsigned short* __restrict__ HB,
                                                 const unsigned short* __restrict__ MB,
                                                 float* __restrict__ gpart) {
  __shared__ __align__(16) char sH[256 * 64];
  __shared__ __align__(16) char sM[256 * 64];
  const int ch = blockIdx.x;
  const int t = threadIdx.x;
  const int w = t >> 6, l = t & 63;
  const int rs = w >> 1, cs = w & 1;            // row-strip 0..3, col-strip 0..1
  const int lg = l >> 4, lr = l & 15;

  f32x4 acc[4][8];
#pragma unroll
  for (int i = 0; i < 4; ++i)
#pragma unroll
    for (int j = 0; j < 8; ++j) acc[i][j] = (f32x4){0.f, 0.f, 0.f, 0.f};

  for (int step = 0; step < 12; ++step) {
    const int k0 = ch * 384 + step * 32;
#pragma unroll
    for (int cc = 0; cc < 2; ++cc) {
      int c = t + cc * 512;                     // chunk id in [0,1024)
      int row = c >> 2, kc = c & 3;             // 4x16B chunks per row
      size_t goff = (size_t)row * GK + k0 + kc * 8;
      u16x8 vh = *(const u16x8*)(HB + goff);
      u16x8 vm = *(const u16x8*)(MB + goff);
      int lo = row * 64 + ((kc * 16) ^ (((row >> 1) & 3) << 4));
      *(u16x8*)(sH + lo) = vh;
      *(u16x8*)(sM + lo) = vm;
    }
    __syncthreads();

    bf16x8 Ah[4], Am[4];
#pragma unroll
    for (int tr = 0; tr < 4; ++tr) {
      int row = rs * 64 + tr * 16 + lr;
      int off = row * 64 + ((lg * 16) ^ (((row >> 1) & 3) << 4));
      Ah[tr] = *(const bf16x8*)(sH + off);
      Am[tr] = *(const bf16x8*)(sM + off);
    }
#pragma unroll
    for (int tc = 0; tc < 8; ++tc) {
      int col = cs * 128 + tc * 16 + lr;
      int boff = col * 64 + ((lg * 16) ^ (((col >> 1) & 3) << 4));
      bf16x8 Bh = *(const bf16x8*)(sH + boff);
      bf16x8 Bm = *(const bf16x8*)(sM + boff);
#pragma unroll
      for (int tr = 0; tr < 4; ++tr) {
        acc[tr][tc] = __builtin_amdgcn_mfma_f32_16x16x32_bf16(Ah[tr], Bh, acc[tr][tc], 0, 0, 0);
        acc[tr][tc] = __builtin_amdgcn_mfma_f32_16x16x32_bf16(Ah[tr], Bm, acc[tr][tc], 0, 0, 0);
        acc[tr][tc] = __builtin_amdgcn_mfma_f32_16x16x32_bf16(Am[tr], Bh, acc[tr][tc], 0, 0, 0);
      }
    }
    __syncthreads();
  }

  float* outp = gpart + (size_t)ch * 65536;
#pragma unroll
  for (int tr = 0; tr < 4; ++tr)
#pragma unroll
    for (int tc = 0; tc < 8; ++tc) {
#pragma unroll
      for (int r = 0; r < 4; ++r) {
        int grow = rs * 64 + tr * 16 + lg * 4 + r;   // C/D: row=(lane>>4)*4+reg
        int gcol = cs * 128 + tc * 16 + lr;          // C/D: col=lane&15
        outp[grow * 256 + gcol] = acc[tr][tc][r];
      }
    }
}

__global__ void reduceG(const float* __restrict__ gpart, double* __restrict__ G) {
  int i = blockIdx.x, j = threadIdx.x;
  double s = 0.0;
  for (int c = 0; c < NCH; ++c) s += (double)gpart[(size_t)c * 65536 + i * 256 + j];
  G[i * 256 + j] = s;
}

// ---------------- Stage B2+C+D fused: k-means + ordering + selection --------
// Single block, 256 threads. S (60x256 doubles) lives in LDS for all 10
// iterations; member-sum updates are incremental (only reassigned points read
// their G row). Empty-cluster freeze is done in place: frozen rows are never
// decremented (their last live member-sum IS the frozen centroid*N), rows of
// clusters that go frozen->live are zeroed before arrivals accumulate.
__global__ __launch_bounds__(256) void kmeans_all(
    const double* __restrict__ G,
    int* __restrict__ orderws, int* __restrict__ idxws,
    int* __restrict__ mcount, int* __restrict__ mlist, int* __restrict__ Nout,
    float* __restrict__ out_idx, float* __restrict__ out_ts, float* __restrict__ out_w) {
  __shared__ double S[KC][256];                 // 120 KB: member sums (gram space)
  __shared__ double Qs[KC], qnn[KC], invn[KC];
  __shared__ double tcol[256];
  __shared__ int Ns[KC], liv[KC], cnt[KC];
  __shared__ int aOld[256], aNew[256];
  __shared__ int chg[256];
  __shared__ int nchg;
  __shared__ unsigned long long membw[KC][4];   // membership bitmask per cluster
  __shared__ unsigned long long redk[256];
  __shared__ int counts64[64], tsum64[64];
  __shared__ float times[KC], wts[KC];
  __shared__ int ord[KC], ord2[KC], sel[NSEL];

  const int i = threadIdx.x;
  const int wv = i >> 6, lane = i & 63;
  const double gii = G[i * 257];

  // ---- init: centroids = rows round(linspace(0,255,60)) ----
  if (i < KC) {
    int pj = (int)rint((double)i * 255.0 / 59.0);
    double q = G[(size_t)pj * 257];
    Qs[i] = q; qnn[i] = q; invn[i] = 1.0;
    Ns[i] = 1; liv[i] = 0;                      // pseudo-frozen: iter1 rebuilds live rows
  }
  aOld[i] = -1;
  for (int jb = 0; jb < KC; jb += 8) {          // batched loads to hide latency
    double g[8];
#pragma unroll
    for (int k = 0; k < 8; ++k) {
      int j = jb + k;
      int pj = (j < KC) ? (int)rint((double)j * 255.0 / 59.0) : 0;
      g[k] = G[(size_t)pj * 256 + i];
    }
#pragma unroll
    for (int k = 0; k < 8; ++k) if (jb + k < KC) S[jb + k][i] = g[k];
  }
  for (int j = 0; j < KC; ++j) {
    int pj = (int)rint((double)j * 255.0 / 59.0);
    unsigned long long mm = __ballot(i == pj);
    if (lane == 0) membw[j][wv] = mm;
  }
  __syncthreads();

  for (int it = 0; it < KM_IT; ++it) {
    // A: assignment (first-min tie-break, matches jnp.argmin)
    double bd = 1e300; int best = 0;
    for (int j = 0; j < KC; ++j) {
      double dd = gii + qnn[j] - 2.0 * S[j][i] * invn[j];
      if (dd < bd) { bd = dd; best = j; }
    }
    aNew[i] = best;
    if (i < KC) cnt[i] = 0;
    __syncthreads();
    atomicAdd(&cnt[best], 1);
    __syncthreads();
    // change list in deterministic (ascending p) order
    if (i == 0) {
      int m = 0;
      for (int p = 0; p < 256; ++p) if (aNew[p] != aOld[p]) chg[m++] = p;
      nchg = m;
    }
    // B: zero rows going frozen->live (arrivals rebuild them from scratch)
    for (int j = 0; j < KC; ++j)
      if (cnt[j] > 0 && !liv[j]) S[j][i] = 0.0;
    __syncthreads();
    // C: incremental deltas; thread i owns column i of every S row
    int m = nchg;
    for (int b = 0; b < m; b += 16) {
      double g[16]; int pp[16];
#pragma unroll
      for (int k = 0; k < 16; ++k) {
        int idx = b + k;
        pp[k] = chg[(idx < m) ? idx : (m - 1)];
        g[k] = G[(size_t)pp[k] * 256 + i];
      }
#pragma unroll
      for (int k = 0; k < 16; ++k) {
        if (b + k < m) {
          int p = pp[k];
          int jn = aNew[p], jo = aOld[p];
          // decrement only live-and-staying-live sources; a newly-empty
          // cluster keeps its pre-departure sum == frozen centroid*N
          if (jo >= 0 && cnt[jo] > 0) S[jo][i] -= g[k];
          S[jn][i] += g[k];
        }
      }
    }
    tcol[i] = S[best][i];
    __syncthreads();                             // tcol ready; aOld reads done
    // state update for live clusters
    for (int j = 0; j < KC; ++j) {
      if (cnt[j] > 0) {
        unsigned long long mm = __ballot(best == j);
        if (lane == 0) membw[j][wv] = mm;
      }
    }
    if (i < KC) {
      int j = i;
      if (cnt[j] > 0) {
        double q = 0.0;
        for (int p = 0; p < 256; ++p) if (aNew[p] == j) q += tcol[p];
        double n = (double)cnt[j];
        Qs[j] = q; Ns[j] = cnt[j]; liv[j] = 1;
        invn[j] = 1.0 / n;
        qnn[j] = q / (n * n);
      } else {
        liv[j] = 0;                              // freeze: keep Qs/qnn/invn/Ns
      }
    }
    aOld[i] = aNew[i];
    __syncthreads();
  }

  // ---- final assignment + ordering (port of final_kernel) ----
  double bd = 1e300; int best = 0;
  for (int j = 0; j < KC; ++j) {
    double dd = gii + qnn[j] - 2.0 * S[j][i] * invn[j];
    if (dd < bd) { bd = dd; best = j; }
  }
  if (i < 64) { counts64[i] = 0; tsum64[i] = 0; }
  __syncthreads();
  atomicAdd(&counts64[best], 1);
  atomicAdd(&tsum64[best], i);
  __syncthreads();
  if (i < KC) times[i] = (float)tsum64[i] / fmaxf((float)counts64[i], 1.0f);
  __syncthreads();
  if (i < KC) {                                  // stable argsort(times)
    float ti = times[i]; int r = 0;
    for (int s = 0; s < KC; ++s) {
      float ts = times[s];
      r += (ts < ti) || (ts == ti && s < i);
    }
    ord[r] = i;
  }
  __syncthreads();
  if (i < KC) wts[i] = (float)counts64[ord[i]];
  __syncthreads();
  if (i < KC) {                                  // stable argsort(-wts)
    float wi = wts[i]; int r = 0;
    for (int s = 0; s < KC; ++s) {
      float wsv = wts[s];
      r += (wsv > wi) || (wsv == wi && s < i);
    }
    ord2[r] = i;
  }
  __syncthreads();
  if (i < KC) {
    int j = ord[i];
    orderws[i] = j;
    out_w[i] = (float)counts64[j];
    out_ts[i] = rintf(times[j]);
    Nout[i] = Ns[i];
  }
  if (i < NSEL) sel[i] = ord[ord2[i]];
  if (i < KC) {                                  // member lists (last-live membership)
    int c = 0;
    for (int w = 0; w < 4; ++w) {
      unsigned long long mm = membw[i][w];
      while (mm) {
        int b = __builtin_ctzll(mm);
        mlist[i * 256 + (c++)] = w * 64 + b;
        mm &= mm - 1;
      }
    }
    mcount[i] = c;
  }
  __syncthreads();

  // ---- distidx: 30 argmins over 256 points (tie -> lowest index) ----
  for (int s = 0; s < NSEL; ++s) {
    int j = sel[s];
    double v = gii + qnn[j] - 2.0 * S[j][i] * invn[j];
    float dd = sqrtf(fmaxf((float)v, 0.0f));
    redk[i] = (((unsigned long long)__float_as_uint(dd)) << 32) | (unsigned)i;
    __syncthreads();
    for (int off = 128; off > 0; off >>= 1) {
      if (i < off) {
        unsigned long long o = redk[i + off];
        if (o < redk[i]) redk[i] = o;
      }
      __syncthreads();
    }
    if (i == 0) {
      int bi = (int)(redk[0] & 0xffffffffULL);
      idxws[s] = bi;
      out_idx[s] = (float)bi;
    }
    __syncthreads();
  }
}

// ---------------- Stage E fused: gather_spa + write_tem ---------------------
// blocks [0,8820): spa gather (float4 copy of 30 selected frames)
// blocks [8820,11040): tem centroids, 16B loads, 2xfloat4 stores
__global__ void tail_kernel(const float* __restrict__ x, const int* __restrict__ idxws,
                            const __hip_bfloat16* __restrict__ HB,
                            const __hip_bfloat16* __restrict__ MB,
                            const int* __restrict__ orderws,
                            const int* __restrict__ mcount, const int* __restrict__ mlist,
                            const int* __restrict__ N,
                            float* __restrict__ out_cat, float* __restrict__ out_tem) {
  int bid = blockIdx.x;
  if (bid < 8820) {
    int pos = bid * 256 + threadIdx.x;           // 30*75264 float4s
    int s = pos / 75264;
    int o = pos - s * 75264;
    ((float4*)out_cat)[pos] = ((const float4*)x)[(size_t)idxws[s] * 75264 + o];
  } else {
    int b2 = bid - 8820;
    int r = b2 / 37, g = b2 - r * 37;
    int col8 = g * 256 + threadIdx.x;            // 9408 groups of 8 elements
    if (col8 >= 9408) return;
    int j = orderws[r];
    int cntm = mcount[j];
    float n = (float)N[j];
    float acc[8];
#pragma unroll
    for (int k = 0; k < 8; ++k) acc[k] = 0.f;
    for (int m = 0; m < cntm; ++m) {
      int p = mlist[j * 256 + m];
      u16x8 hv = *(const u16x8*)((const unsigned short*)HB + (size_t)p * GK + (size_t)col8 * 8);
      u16x8 mv = *(const u16x8*)((const unsigned short*)MB + (size_t)p * GK + (size_t)col8 * 8);
#pragma unroll
      for (int k = 0; k < 8; ++k) acc[k] += b2f(hv[k]) + b2f(mv[k]);
    }
    float4 o0 = make_float4(acc[0] / n, acc[1] / n, acc[2] / n, acc[3] / n);
    float4 o1 = make_float4(acc[4] / n, acc[5] / n, acc[6] / n, acc[7] / n);
    float4* dst = (float4*)out_tem + (size_t)r * 18816 + (size_t)col8 * 2;
    dst[0] = o0;
    dst[1] = o1;
  }
}

extern "C" void kernel_launch(void* const* d_in, const int* in_sizes, int n_in,
                              void* d_out, int out_size, void* d_ws, size_t ws_size,
                              hipStream_t stream) {
  const float* x = (const float*)d_in[0];
  char* ws = (char*)d_ws;
  size_t off = 0;
  __hip_bfloat16* HB = (__hip_bfloat16*)(ws + off); off += (size_t)19267584 * 2;  // 38.5 MB
  __hip_bfloat16* MB = (__hip_bfloat16*)(ws + off); off += (size_t)19267584 * 2;  // 38.5 MB
  double* G    = (double*)(ws + off);    off += (size_t)65536 * 8;
  int* orderws = (int*)(ws + off);       off += 256;
  int* idxws   = (int*)(ws + off);       off += 256;
  int* mcount  = (int*)(ws + off);       off += 256;
  int* Nws     = (int*)(ws + off);       off += 256;
  int* mlist   = (int*)(ws + off);       off += (size_t)KC * 256 * 4;

  float* out = (float*)d_out;
  float* gpart = out;  // NCH*256KB = 51.4 MB scratch inside cat_x region; overwritten later

  const size_t o_cat = 0;
  const size_t o_tem = 9031680;
  const size_t o_idx = 13547520;
  const size_t o_ts  = o_idx + 30;
  const size_t o_w   = o_ts + 60;

  pool_kernel<<<75264, 256, 0, stream>>>(x, HB, MB);
  gram_mfma<<<NCH, 512, 0, stream>>>((const unsigned short*)HB, (const unsigned short*)MB, gpart);
  reduceG<<<256, 256, 0, stream>>>(gpart, G);
  kmeans_all<<<1, 256, 0, stream>>>(G, orderws, idxws, mcount, mlist, Nws,
                                    out + o_idx, out + o_ts, out + o_w);
  tail_kernel<<<8820 + KC * 37, 256, 0, stream>>>(x, idxws, HB, MB, orderws, mcount, mlist,
                                                  Nws, out + o_cat, out + o_tem);
}

// Round 2
// 302.902 us; speedup vs baseline: 2.2357x; 2.2357x over previous
//
#include <hip/hip_runtime.h>
#include <hip/hip_bf16.h>
#include <math.h>

#define GK 75264      // per-frame feature dim (64*1176)
#define NF 256        // frames
#define KC 60         // clusters
#define NSEL 30       // selected spatial centroids
#define NCH 196       // gram split-K channels (K=384 each, 12 steps of 32)
#define KM_IT 10

typedef __attribute__((ext_vector_type(8))) short bf16x8;
typedef __attribute__((ext_vector_type(4))) float f32x4;
typedef __attribute__((ext_vector_type(8))) unsigned short u16x8;

__device__ __forceinline__ float b2f(unsigned short u) {
  union { unsigned u32; float f; } c; c.u32 = ((unsigned)u) << 16; return c.f;
}

// ---------------- Stage A: temporal 2x2 pooling -> bf16 split (H, M) --------
__global__ void pool_kernel(const float* __restrict__ x,
                            __hip_bfloat16* __restrict__ H,
                            __hip_bfloat16* __restrict__ M) {
  unsigned id = blockIdx.x * 256u + threadIdx.x;   // exactly 19,267,584 threads
  unsigned m = id / 1176u, o = id - m * 1176u;
  unsigned t = m >> 6, r = m & 63u;
  unsigned ih = r >> 4, iw = (r >> 2) & 3u, s = r & 3u;
  unsigned i8 = ih * 2u + (s >> 1), j8 = iw * 2u + (s & 1u);
  unsigned c = o / 392u, o2 = o - c * 392u;
  unsigned d = o2 / 196u, o3 = o2 - d * 196u;
  unsigned e = o3 / 14u, f = o3 - e * 14u;
  unsigned a = (e >= 7u) ? 1u : 0u, b = (f >= 7u) ? 1u : 0u;
  unsigned ee = 2u * e - 14u * a, ff = 2u * f - 14u * b;
  unsigned xrow = ((t * 8u + i8) * 8u + j8) * 4u + a * 2u + b;
  unsigned xcol = ((c * 2u + d) * 14u + ee) * 14u + ff;
  const float* base = x + (size_t)xrow * 1176u + xcol;
  float v = 0.25f * ((base[0] + base[1]) + (base[14] + base[15]));
  __hip_bfloat16 hb = __float2bfloat16(v);
  float hf = __bfloat162float(hb);
  __hip_bfloat16 mb = __float2bfloat16(v - hf);
  H[id] = hb;
  M[id] = mb;
}

// ---------------- Stage B1: Gram via bf16 MFMA, 3-product split-float -------
// G = H.H^T + H.M^T + M.H^T  (exact to ~2^-18 relative; mm term negligible).
__global__ __launch_bounds__(512) void gram_mfma(const unsigned short* __restrict__ HB,
                                                 const unsigned short* __restrict__ MB,
                                                 float* __restrict__ gpart) {
  __shared__ __align__(16) char sH[256 * 64];
  __shared__ __align__(16) char sM[256 * 64];
  const int ch = blockIdx.x;
  const int t = threadIdx.x;
  const int w = t >> 6, l = t & 63;
  const int rs = w >> 1, cs = w & 1;            // row-strip 0..3, col-strip 0..1
  const int lg = l >> 4, lr = l & 15;

  f32x4 acc[4][8];
#pragma unroll
  for (int i = 0; i < 4; ++i)
#pragma unroll
    for (int j = 0; j < 8; ++j) acc[i][j] = (f32x4){0.f, 0.f, 0.f, 0.f};

  for (int step = 0; step < 12; ++step) {
    const int k0 = ch * 384 + step * 32;
#pragma unroll
    for (int cc = 0; cc < 2; ++cc) {
      int c = t + cc * 512;                     // chunk id in [0,1024)
      int row = c >> 2, kc = c & 3;             // 4x16B chunks per row
      size_t goff = (size_t)row * GK + k0 + kc * 8;
      u16x8 vh = *(const u16x8*)(HB + goff);
      u16x8 vm = *(const u16x8*)(MB + goff);
      int lo = row * 64 + ((kc * 16) ^ (((row >> 1) & 3) << 4));
      *(u16x8*)(sH + lo) = vh;
      *(u16x8*)(sM + lo) = vm;
    }
    __syncthreads();

    bf16x8 Ah[4], Am[4];
#pragma unroll
    for (int tr = 0; tr < 4; ++tr) {
      int row = rs * 64 + tr * 16 + lr;
      int off = row * 64 + ((lg * 16) ^ (((row >> 1) & 3) << 4));
      Ah[tr] = *(const bf16x8*)(sH + off);
      Am[tr] = *(const bf16x8*)(sM + off);
    }
#pragma unroll
    for (int tc = 0; tc < 8; ++tc) {
      int col = cs * 128 + tc * 16 + lr;
      int boff = col * 64 + ((lg * 16) ^ (((col >> 1) & 3) << 4));
      bf16x8 Bh = *(const bf16x8*)(sH + boff);
      bf16x8 Bm = *(const bf16x8*)(sM + boff);
#pragma unroll
      for (int tr = 0; tr < 4; ++tr) {
        acc[tr][tc] = __builtin_amdgcn_mfma_f32_16x16x32_bf16(Ah[tr], Bh, acc[tr][tc], 0, 0, 0);
        acc[tr][tc] = __builtin_amdgcn_mfma_f32_16x16x32_bf16(Ah[tr], Bm, acc[tr][tc], 0, 0, 0);
        acc[tr][tc] = __builtin_amdgcn_mfma_f32_16x16x32_bf16(Am[tr], Bh, acc[tr][tc], 0, 0, 0);
      }
    }
    __syncthreads();
  }

  float* outp = gpart + (size_t)ch * 65536;
#pragma unroll
  for (int tr = 0; tr < 4; ++tr)
#pragma unroll
    for (int tc = 0; tc < 8; ++tc) {
#pragma unroll
      for (int r = 0; r < 4; ++r) {
        int grow = rs * 64 + tr * 16 + lg * 4 + r;   // C/D: row=(lane>>4)*4+reg
        int gcol = cs * 128 + tc * 16 + lr;          // C/D: col=lane&15
        outp[grow * 256 + gcol] = acc[tr][tc][r];
      }
    }
}

__global__ void reduceG(const float* __restrict__ gpart, double* __restrict__ G) {
  int i = blockIdx.x, j = threadIdx.x;
  double s = 0.0;
  for (int c = 0; c < NCH; ++c) s += (double)gpart[(size_t)c * 65536 + i * 256 + j];
  G[i * 256 + j] = s;
}

// ---------------- Stage B2+C+D fused: k-means + ordering + selection --------
// Single block, 256 threads (4 waves). Latency-disciplined rewrite:
//  - change list = per-wave __ballot -> 4 uniform u64 words, iterated as
//    statically-unrolled 8-wide batches (registers, not scratch)
//  - Q[j] = sum over MEMBER bits only (same ascending-p fp64 order as before
//    -> bit-identical rounding to the verified serial version)
//  - distidx = __shfl_xor wave min-reduce: 1 barrier total (was ~300)
//  - frozen->live zeroing via uniform ballot mask (usually empty)
__global__ __launch_bounds__(256) void kmeans_all(
    const double* __restrict__ G,
    int* __restrict__ orderws, int* __restrict__ idxws,
    int* __restrict__ mcount, int* __restrict__ mlist, int* __restrict__ Nout,
    float* __restrict__ out_idx, float* __restrict__ out_ts, float* __restrict__ out_w) {
  __shared__ double S[KC][256];                 // 120 KB member sums (gram space)
  __shared__ double Qs[KC], qnn[KC], invn[KC];
  __shared__ int Ns[KC], liv[64];
  __shared__ int cbuf[2][64];                   // double-buffered counts
  __shared__ int aNewL[256], aOldL[256];
  __shared__ unsigned long long chgw[4];        // changed-point bitmask
  __shared__ unsigned long long membw[KC][4];   // membership bitmask per cluster
  __shared__ unsigned long long part[NSEL][4];  // distidx per-wave partials
  __shared__ int counts64[64], tsum64[64];
  __shared__ float times[KC], wts[KC];
  __shared__ int ord[KC], ord2[KC], sel[NSEL];

  const int i = threadIdx.x;
  const int wv = i >> 6, lane = i & 63;
  const double gii = G[i * 257];

  // ---- init: centroids = rows round(linspace(0,255,60)) ----
  if (i < KC) {
    int pj = (int)rint((double)i * 255.0 / 59.0);
    double q = G[(size_t)pj * 257];
    Qs[i] = q; qnn[i] = q; invn[i] = 1.0;
    Ns[i] = 1; liv[i] = 0;                      // pseudo-frozen: iter1 rebuilds live rows
  }
  if (i >= KC && i < 64) liv[i] = 1;            // pad lanes: never "frozen->live"
  if (i < 64) { cbuf[0][i] = 0; cbuf[1][i] = 0; }
  aOldL[i] = -1;
  int aOldReg = -1;
  for (int jb = 0; jb < KC; jb += 8) {          // batched centroid-row loads
    double g[8];
#pragma unroll
    for (int k = 0; k < 8; ++k) {
      int j = jb + k;
      int pj = (j < KC) ? (int)rint((double)j * 255.0 / 59.0) : 0;
      g[k] = G[(size_t)pj * 256 + i];
    }
#pragma unroll
    for (int k = 0; k < 8; ++k) if (jb + k < KC) S[jb + k][i] = g[k];
  }
  for (int j = 0; j < KC; ++j) {
    int pj = (int)rint((double)j * 255.0 / 59.0);
    unsigned long long mm = __ballot(i == pj);
    if (lane == 0) membw[j][wv] = mm;
  }
  __syncthreads();

  int cur = 0;
  for (int it = 0; it < KM_IT; ++it) {
    // ---- A: assignment (first-min tie-break, matches jnp.argmin) ----
    double bd = 1e300; int best = 0;
    for (int j = 0; j < KC; ++j) {
      double dd = gii + qnn[j] - 2.0 * S[j][i] * invn[j];
      if (dd < bd) { bd = dd; best = j; }
    }
    aNewL[i] = best;
    atomicAdd(&cbuf[cur][best], 1);
    unsigned long long cw = __ballot(best != aOldReg);
    if (lane == 0) chgw[wv] = cw;
    if (i < 64) cbuf[cur ^ 1][i] = 0;           // pre-zero next iter's buffer
    __syncthreads();

    // ---- C: refresh live membership masks ----
    for (int j = 0; j < KC; ++j) {
      unsigned long long mm = __ballot(best == j);
      if (lane == 0 && cbuf[cur][j] > 0) membw[j][wv] = mm;
    }
    // zero rows going frozen->live (column-exclusive: no barrier needed
    // between the zero and this thread's own subsequent increments)
    {
      unsigned long long zb = __ballot(lane < KC && cbuf[cur][lane] > 0 && liv[lane] == 0);
      while (zb) { int j = __builtin_ctzll(zb); zb &= zb - 1; S[j][i] = 0.0; }
    }
    // incremental deltas over changed points, ascending p (same fp64 order
    // as the verified serial version); 8-wide static batches
#pragma unroll
    for (int wi = 0; wi < 4; ++wi) {
      unsigned long long mm = chgw[wi];
      while (mm) {
        int pb[8];
#pragma unroll
        for (int k = 0; k < 8; ++k) {
          if (mm) { int b = __builtin_ctzll(mm); mm &= mm - 1; pb[k] = wi * 64 + b; }
          else pb[k] = -1;
        }
        double g[8]; int jn[8], jo[8];
#pragma unroll
        for (int k = 0; k < 8; ++k) {
          if (pb[k] >= 0) {
            jn[k] = aNewL[pb[k]]; jo[k] = aOldL[pb[k]];
            g[k] = G[(size_t)pb[k] * 256 + i];
          }
        }
#pragma unroll
        for (int k = 0; k < 8; ++k) {
          if (pb[k] >= 0) {
            if (jo[k] >= 0 && cbuf[cur][jo[k]] > 0) S[jo[k]][i] -= g[k];
            S[jn[k]][i] += g[k];
          }
        }
      }
    }
    __syncthreads();

    // ---- D: per-cluster state update (members-only Q sum, ascending p) ----
    if (i < KC) {
      int c = cbuf[cur][i];
      if (c > 0) {
        double q = 0.0;
#pragma unroll
        for (int wq = 0; wq < 4; ++wq) {
          unsigned long long mm = membw[i][wq];
          while (mm) { int b = __builtin_ctzll(mm); mm &= mm - 1; q += S[i][wq * 64 + b]; }
        }
        double n = (double)c;
        Qs[i] = q; Ns[i] = c; liv[i] = 1;
        invn[i] = 1.0 / n;
        qnn[i] = q / (n * n);
      } else {
        liv[i] = 0;                              // freeze: keep Qs/qnn/invn/Ns
      }
    }
    aOldReg = best; aOldL[i] = best;
    cur ^= 1;
    __syncthreads();
  }

  // ---- final assignment + ordering ----
  double bd = 1e300; int best = 0;
  for (int j = 0; j < KC; ++j) {
    double dd = gii + qnn[j] - 2.0 * S[j][i] * invn[j];
    if (dd < bd) { bd = dd; best = j; }
  }
  if (i < 64) { counts64[i] = 0; tsum64[i] = 0; }
  __syncthreads();
  atomicAdd(&counts64[best], 1);
  atomicAdd(&tsum64[best], i);
  __syncthreads();
  if (i < KC) times[i] = (float)tsum64[i] / fmaxf((float)counts64[i], 1.0f);
  __syncthreads();
  if (i < KC) {                                  // stable argsort(times)
    float ti = times[i]; int r = 0;
    for (int s = 0; s < KC; ++s) {
      float ts = times[s];
      r += (ts < ti) || (ts == ti && s < i);
    }
    ord[r] = i;
  }
  __syncthreads();
  if (i < KC) wts[i] = (float)counts64[ord[i]];
  __syncthreads();
  if (i < KC) {                                  // stable argsort(-wts)
    float wi = wts[i]; int r = 0;
    for (int s = 0; s < KC; ++s) {
      float wsv = wts[s];
      r += (wsv > wi) || (wsv == wi && s < i);
    }
    ord2[r] = i;
  }
  __syncthreads();
  if (i < KC) {
    int j = ord[i];
    orderws[i] = j;
    out_w[i] = (float)counts64[j];
    out_ts[i] = rintf(times[j]);
    Nout[i] = Ns[i];
  }
  if (i < NSEL) sel[i] = ord[ord2[i]];
  if (i < KC) {                                  // member lists (last-live membership)
    int c = 0;
#pragma unroll
    for (int w = 0; w < 4; ++w) {
      unsigned long long mm = membw[i][w];
      while (mm) {
        int b = __builtin_ctzll(mm);
        mlist[i * 256 + (c++)] = w * 64 + b;
        mm &= mm - 1;
      }
    }
    mcount[i] = c;
  }
  __syncthreads();

  // ---- distidx: 30 argmins via wave shuffle reduce (1 barrier total) ----
  for (int s = 0; s < NSEL; ++s) {
    int j = sel[s];
    double v = gii + qnn[j] - 2.0 * S[j][i] * invn[j];
    float dd = sqrtf(fmaxf((float)v, 0.0f));
    unsigned long long key = (((unsigned long long)__float_as_uint(dd)) << 32) | (unsigned)i;
#pragma unroll
    for (int o = 32; o > 0; o >>= 1) {
      unsigned long long other = __shfl_xor(key, o, 64);
      if (other < key) key = other;
    }
    if (lane == 0) part[s][wv] = key;
  }
  __syncthreads();
  if (i < NSEL) {
    unsigned long long k0 = part[i][0];
#pragma unroll
    for (int w = 1; w < 4; ++w) if (part[i][w] < k0) k0 = part[i][w];
    int bi = (int)(k0 & 0xffffffffULL);
    idxws[i] = bi;
    out_idx[i] = (float)bi;
  }
}

// ---------------- Stage E fused: gather_spa + write_tem ---------------------
__global__ void tail_kernel(const float* __restrict__ x, const int* __restrict__ idxws,
                            const __hip_bfloat16* __restrict__ HB,
                            const __hip_bfloat16* __restrict__ MB,
                            const int* __restrict__ orderws,
                            const int* __restrict__ mcount, const int* __restrict__ mlist,
                            const int* __restrict__ N,
                            float* __restrict__ out_cat, float* __restrict__ out_tem) {
  int bid = blockIdx.x;
  if (bid < 8820) {
    int pos = bid * 256 + threadIdx.x;           // 30*75264 float4s
    int s = pos / 75264;
    int o = pos - s * 75264;
    ((float4*)out_cat)[pos] = ((const float4*)x)[(size_t)idxws[s] * 75264 + o];
  } else {
    int b2 = bid - 8820;
    int r = b2 / 37, g = b2 - r * 37;
    int col8 = g * 256 + threadIdx.x;            // 9408 groups of 8 elements
    if (col8 >= 9408) return;
    int j = orderws[r];
    int cntm = mcount[j];
    float n = (float)N[j];
    float acc[8];
#pragma unroll
    for (int k = 0; k < 8; ++k) acc[k] = 0.f;
    for (int m = 0; m < cntm; ++m) {
      int p = mlist[j * 256 + m];
      u16x8 hv = *(const u16x8*)((const unsigned short*)HB + (size_t)p * GK + (size_t)col8 * 8);
      u16x8 mv = *(const u16x8*)((const unsigned short*)MB + (size_t)p * GK + (size_t)col8 * 8);
#pragma unroll
      for (int k = 0; k < 8; ++k) acc[k] += b2f(hv[k]) + b2f(mv[k]);
    }
    float4 o0 = make_float4(acc[0] / n, acc[1] / n, acc[2] / n, acc[3] / n);
    float4 o1 = make_float4(acc[4] / n, acc[5] / n, acc[6] / n, acc[7] / n);
    float4* dst = (float4*)out_tem + (size_t)r * 18816 + (size_t)col8 * 2;
    dst[0] = o0;
    dst[1] = o1;
  }
}

extern "C" void kernel_launch(void* const* d_in, const int* in_sizes, int n_in,
                              void* d_out, int out_size, void* d_ws, size_t ws_size,
                              hipStream_t stream) {
  const float* x = (const float*)d_in[0];
  char* ws = (char*)d_ws;
  size_t off = 0;
  __hip_bfloat16* HB = (__hip_bfloat16*)(ws + off); off += (size_t)19267584 * 2;  // 38.5 MB
  __hip_bfloat16* MB = (__hip_bfloat16*)(ws + off); off += (size_t)19267584 * 2;  // 38.5 MB
  double* G    = (double*)(ws + off);    off += (size_t)65536 * 8;
  int* orderws = (int*)(ws + off);       off += 256;
  int* idxws   = (int*)(ws + off);       off += 256;
  int* mcount  = (int*)(ws + off);       off += 256;
  int* Nws     = (int*)(ws + off);       off += 256;
  int* mlist   = (int*)(ws + off);       off += (size_t)KC * 256 * 4;

  float* out = (float*)d_out;
  float* gpart = out;  // NCH*256KB = 51.4 MB scratch inside cat_x region; overwritten later

  const size_t o_cat = 0;
  const size_t o_tem = 9031680;
  const size_t o_idx = 13547520;
  const size_t o_ts  = o_idx + 30;
  const size_t o_w   = o_ts + 60;

  pool_kernel<<<75264, 256, 0, stream>>>(x, HB, MB);
  gram_mfma<<<NCH, 512, 0, stream>>>((const unsigned short*)HB, (const unsigned short*)MB, gpart);
  reduceG<<<256, 256, 0, stream>>>(gpart, G);
  kmeans_all<<<1, 256, 0, stream>>>(G, orderws, idxws, mcount, mlist, Nws,
                                    out + o_idx, out + o_ts, out + o_w);
  tail_kernel<<<8820 + KC * 37, 256, 0, stream>>>(x, idxws, HB, MB, orderws, mcount, mlist,
                                                  Nws, out + o_cat, out + o_tem);
}

// Round 4
// 233.552 us; speedup vs baseline: 2.8996x; 1.2969x over previous
//
#include <hip/hip_runtime.h>
#include <hip/hip_bf16.h>
#include <math.h>

#define GK 75264      // per-frame feature dim (64*1176)
#define NF 256        // frames
#define KC 60         // clusters
#define NSEL 30       // selected spatial centroids
#define NCH 196       // gram split-K channels (K=384 each, 12 steps of 32)
#define KM_IT 10

typedef __attribute__((ext_vector_type(8))) short bf16x8;
typedef __attribute__((ext_vector_type(4))) float f32x4;
typedef __attribute__((ext_vector_type(8))) unsigned short u16x8;

__device__ __forceinline__ float b2f(unsigned short u) {
  union { unsigned u32; float f; } c; c.u32 = ((unsigned)u) << 16; return c.f;
}

// ---------------- Stage A: temporal 2x2 pooling -> bf16 split (H, M) --------
__global__ void pool_kernel(const float* __restrict__ x,
                            __hip_bfloat16* __restrict__ H,
                            __hip_bfloat16* __restrict__ M) {
  unsigned id = blockIdx.x * 256u + threadIdx.x;   // exactly 19,267,584 threads
  unsigned m = id / 1176u, o = id - m * 1176u;
  unsigned t = m >> 6, r = m & 63u;
  unsigned ih = r >> 4, iw = (r >> 2) & 3u, s = r & 3u;
  unsigned i8 = ih * 2u + (s >> 1), j8 = iw * 2u + (s & 1u);
  unsigned c = o / 392u, o2 = o - c * 392u;
  unsigned d = o2 / 196u, o3 = o2 - d * 196u;
  unsigned e = o3 / 14u, f = o3 - e * 14u;
  unsigned a = (e >= 7u) ? 1u : 0u, b = (f >= 7u) ? 1u : 0u;
  unsigned ee = 2u * e - 14u * a, ff = 2u * f - 14u * b;
  unsigned xrow = ((t * 8u + i8) * 8u + j8) * 4u + a * 2u + b;
  unsigned xcol = ((c * 2u + d) * 14u + ee) * 14u + ff;
  const float* base = x + (size_t)xrow * 1176u + xcol;
  float v = 0.25f * ((base[0] + base[1]) + (base[14] + base[15]));
  __hip_bfloat16 hb = __float2bfloat16(v);
  float hf = __bfloat162float(hb);
  __hip_bfloat16 mb = __float2bfloat16(v - hf);
  H[id] = hb;
  M[id] = mb;
}

// ---------------- Stage B1: Gram via bf16 MFMA, 3-product split-float -------
// G = H.H^T + H.M^T + M.H^T  (exact to ~2^-18 relative; mm term negligible).
__global__ __launch_bounds__(512) void gram_mfma(const unsigned short* __restrict__ HB,
                                                 const unsigned short* __restrict__ MB,
                                                 float* __restrict__ gpart) {
  __shared__ __align__(16) char sH[256 * 64];
  __shared__ __align__(16) char sM[256 * 64];
  const int ch = blockIdx.x;
  const int t = threadIdx.x;
  const int w = t >> 6, l = t & 63;
  const int rs = w >> 1, cs = w & 1;            // row-strip 0..3, col-strip 0..1
  const int lg = l >> 4, lr = l & 15;

  f32x4 acc[4][8];
#pragma unroll
  for (int i = 0; i < 4; ++i)
#pragma unroll
    for (int j = 0; j < 8; ++j) acc[i][j] = (f32x4){0.f, 0.f, 0.f, 0.f};

  for (int step = 0; step < 12; ++step) {
    const int k0 = ch * 384 + step * 32;
#pragma unroll
    for (int cc = 0; cc < 2; ++cc) {
      int c = t + cc * 512;                     // chunk id in [0,1024)
      int row = c >> 2, kc = c & 3;             // 4x16B chunks per row
      size_t goff = (size_t)row * GK + k0 + kc * 8;
      u16x8 vh = *(const u16x8*)(HB + goff);
      u16x8 vm = *(const u16x8*)(MB + goff);
      int lo = row * 64 + ((kc * 16) ^ (((row >> 1) & 3) << 4));
      *(u16x8*)(sH + lo) = vh;
      *(u16x8*)(sM + lo) = vm;
    }
    __syncthreads();

    bf16x8 Ah[4], Am[4];
#pragma unroll
    for (int tr = 0; tr < 4; ++tr) {
      int row = rs * 64 + tr * 16 + lr;
      int off = row * 64 + ((lg * 16) ^ (((row >> 1) & 3) << 4));
      Ah[tr] = *(const bf16x8*)(sH + off);
      Am[tr] = *(const bf16x8*)(sM + off);
    }
#pragma unroll
    for (int tc = 0; tc < 8; ++tc) {
      int col = cs * 128 + tc * 16 + lr;
      int boff = col * 64 + ((lg * 16) ^ (((col >> 1) & 3) << 4));
      bf16x8 Bh = *(const bf16x8*)(sH + boff);
      bf16x8 Bm = *(const bf16x8*)(sM + boff);
#pragma unroll
      for (int tr = 0; tr < 4; ++tr) {
        acc[tr][tc] = __builtin_amdgcn_mfma_f32_16x16x32_bf16(Ah[tr], Bh, acc[tr][tc], 0, 0, 0);
        acc[tr][tc] = __builtin_amdgcn_mfma_f32_16x16x32_bf16(Ah[tr], Bm, acc[tr][tc], 0, 0, 0);
        acc[tr][tc] = __builtin_amdgcn_mfma_f32_16x16x32_bf16(Am[tr], Bh, acc[tr][tc], 0, 0, 0);
      }
    }
    __syncthreads();
  }

  float* outp = gpart + (size_t)ch * 65536;
#pragma unroll
  for (int tr = 0; tr < 4; ++tr)
#pragma unroll
    for (int tc = 0; tc < 8; ++tc) {
#pragma unroll
      for (int r = 0; r < 4; ++r) {
        int grow = rs * 64 + tr * 16 + lg * 4 + r;   // C/D: row=(lane>>4)*4+reg
        int gcol = cs * 128 + tc * 16 + lr;          // C/D: col=lane&15
        outp[grow * 256 + gcol] = acc[tr][tc][r];
      }
    }
}

__global__ void reduceG(const float* __restrict__ gpart, double* __restrict__ G) {
  int i = blockIdx.x, j = threadIdx.x;
  double s = 0.0;
  for (int c = 0; c < NCH; ++c) s += (double)gpart[(size_t)c * 65536 + i * 256 + j];
  G[i * 256 + j] = s;
}

// ---------------- Stage B2+C+D fused: k-means + ordering + selection --------
// 1024 threads = 16 waves. ALL decision-feeding arithmetic is fp64 in
// previously-validated summation orders:
//   - assignment: dd = gii + qnn[j] - 2*S[j][i]*invn[j], first-min ascending j
//     (bit-identical to the round-2 passing kernel; split 15/group + exact merge)
//   - S rows: fresh recompute, serial ascending-p fp64 adds from G
//     (bit-identical to the round-0 passing kernel; loads batched 8-wide,
//     add ORDER unchanged — batching changes latency, not bits)
//   - Q: serial ascending-p sum of S[j][p] (bit-identical to round 2)
//   - dirty-skip: membership set unchanged => recompute would reproduce the
//     exact same bits => skip. Init state == fresh-sum of singleton {pj},
//     so the invariant holds from the start; frozen clusters keep state.
__global__ __launch_bounds__(1024) void kmeans_all(
    const double* __restrict__ G,
    int* __restrict__ orderws, int* __restrict__ idxws,
    int* __restrict__ mcount, int* __restrict__ mlist, int* __restrict__ Nout,
    float* __restrict__ out_idx, float* __restrict__ out_ts, float* __restrict__ out_w) {
  __shared__ double S[KC][256];                  // 120 KB member sums (gram space)
  __shared__ double giiL[256];
  __shared__ double pminD[4][256];
  __shared__ int    pminJ[4][256];
  __shared__ __align__(16) double qi[KC][2];     // [0]=qnn=Q/n^2, [1]=invn
  __shared__ int Ns[KC], cnt[KC], dirty[KC];
  __shared__ unsigned long long membw[KC][4];    // committed (last-live) membership
  __shared__ unsigned long long membwN[KC][4];   // this-iteration ballots
  __shared__ int counts64[64], tsum64[64];
  __shared__ float times[KC], wts[KC];
  __shared__ int ord[KC], ord2[KC], sel[NSEL];

  const int tid = threadIdx.x;
  const int i = tid & 255;                       // point / column id
  const int z = tid >> 8;                        // group 0..3 (clusters 15z..15z+14)
  const int lane = tid & 63;
  const int wv4 = (tid >> 6) & 3;                // wave-in-group

  // ---- init: centroids = rows round(linspace(0,255,60)) ----
  if (tid < KC) {
    int pj = (int)rint((double)tid * 255.0 / 59.0);
    double q = G[(size_t)pj * 257];
    qi[tid][0] = q; qi[tid][1] = 1.0;            // Q=gii(pj), n=1
    Ns[tid] = 1; cnt[tid] = 0;
  }
  if (tid < 256) giiL[tid] = G[(size_t)tid * 257];
  {
    double g[15];
#pragma unroll
    for (int t = 0; t < 15; ++t) {
      int j = z * 15 + t;
      int pj = (int)rint((double)j * 255.0 / 59.0);
      g[t] = G[(size_t)pj * 256 + i];
    }
#pragma unroll
    for (int t = 0; t < 15; ++t) S[z * 15 + t][i] = g[t];
  }
  if (z == 0) {
    for (int j = 0; j < KC; ++j) {
      int pj = (int)rint((double)j * 255.0 / 59.0);
      unsigned long long mm = __ballot(i == pj);
      if (lane == 0) membw[j][wv4] = mm;
    }
  }
  __syncthreads();

  const double gii = giiL[i];

  for (int it = 0; it < KM_IT; ++it) {
    // ---- P1: partial argmin over this group's 15 clusters ----
    {
      double bd = 1e300; int bj = 0;
#pragma unroll
      for (int t = 0; t < 15; ++t) {
        int j = z * 15 + t;
        double2 qv = *(const double2*)&qi[j][0];
        double dd = gii + qv.x - 2.0 * S[j][i] * qv.y;
        if (dd < bd) { bd = dd; bj = j; }
      }
      pminD[z][i] = bd; pminJ[z][i] = bj;
    }
    __syncthreads();

    // ---- P2: exact first-min merge (ascending j), counts, ballots ----
    if (z == 0) {
      double bd = pminD[0][i]; int bb = pminJ[0][i];
#pragma unroll
      for (int g = 1; g < 4; ++g) {
        double d2 = pminD[g][i];
        if (d2 < bd) { bd = d2; bb = pminJ[g][i]; }
      }
      atomicAdd(&cnt[bb], 1);
      for (int j = 0; j < KC; ++j) {
        unsigned long long mm = __ballot(bb == j);
        if (lane == 0) membwN[j][wv4] = mm;
      }
    }
    __syncthreads();

    // ---- P2b: dirty detection + membership commit (thread j owns cluster j) ----
    if (tid < KC) {
      int c = cnt[tid];
      int d = 0;
      if (c > 0) {
#pragma unroll
        for (int w = 0; w < 4; ++w) d |= (membwN[tid][w] != membw[tid][w]);
        if (d) {
#pragma unroll
          for (int w = 0; w < 4; ++w) membw[tid][w] = membwN[tid][w];
        }
      }
      dirty[tid] = d;
    }
    __syncthreads();

    // ---- P3: fresh-recompute dirty S rows (fp64, serial ascending adds,
    //          8-wide batched independent loads) ----
    for (int t = 0; t < 15; ++t) {
      int j = z * 15 + t;
      if (!dirty[j]) continue;
      double acc = 0.0;
#pragma unroll
      for (int w = 0; w < 4; ++w) {
        unsigned long long mm = membwN[j][w];     // wave-uniform
        const double* gb = G + (size_t)w * 64 * 256 + i;
        while (mm) {
          double gv[8];
#pragma unroll
          for (int k = 0; k < 8; ++k) gv[k] = 0.0;
#pragma unroll
          for (int k = 0; k < 8; ++k) {
            if (mm) { int b = __builtin_ctzll(mm); mm &= mm - 1; gv[k] = gb[(size_t)b * 256]; }
          }
#pragma unroll
          for (int k = 0; k < 8; ++k) acc += gv[k];  // order preserved; +0.0 no-ops
        }
      }
      S[j][i] = acc;
    }
    __syncthreads();

    // ---- P4: Q for dirty clusters (serial ascending LDS sum, 4-wide loads) ----
    if (tid < KC) {
      if (dirty[tid]) {
        int c = cnt[tid];
        double q = 0.0;
#pragma unroll
        for (int w = 0; w < 4; ++w) {
          unsigned long long mm = membwN[tid][w];
          while (mm) {
            double sv[4];
#pragma unroll
            for (int k = 0; k < 4; ++k) sv[k] = 0.0;
#pragma unroll
            for (int k = 0; k < 4; ++k) {
              if (mm) { int b = __builtin_ctzll(mm); mm &= mm - 1; sv[k] = S[tid][w * 64 + b]; }
            }
#pragma unroll
            for (int k = 0; k < 4; ++k) q += sv[k];
          }
        }
        double n = (double)c;
        Ns[tid] = c;
        qi[tid][1] = 1.0 / n;
        qi[tid][0] = q / (n * n);
      }
      cnt[tid] = 0;
    }
    __syncthreads();
  }

  // ---- final assignment (same split + merge) ----
  {
    double bd = 1e300; int bj = 0;
#pragma unroll
    for (int t = 0; t < 15; ++t) {
      int j = z * 15 + t;
      double2 qv = *(const double2*)&qi[j][0];
      double dd = gii + qv.x - 2.0 * S[j][i] * qv.y;
      if (dd < bd) { bd = dd; bj = j; }
    }
    pminD[z][i] = bd; pminJ[z][i] = bj;
  }
  if (tid < 64) { counts64[tid] = 0; tsum64[tid] = 0; }
  __syncthreads();
  if (z == 0) {
    double bd = pminD[0][i]; int bb = pminJ[0][i];
#pragma unroll
    for (int g = 1; g < 4; ++g) {
      double d2 = pminD[g][i];
      if (d2 < bd) { bd = d2; bb = pminJ[g][i]; }
    }
    atomicAdd(&counts64[bb], 1);
    atomicAdd(&tsum64[bb], i);
  }
  __syncthreads();
  if (tid < KC) times[tid] = (float)tsum64[tid] / fmaxf((float)counts64[tid], 1.0f);
  __syncthreads();
  if (tid < KC) {                                // stable argsort(times)
    float ti = times[tid]; int r = 0;
    for (int s = 0; s < KC; ++s) {
      float ts = times[s];
      r += (ts < ti) || (ts == ti && s < tid);
    }
    ord[r] = tid;
  }
  __syncthreads();
  if (tid < KC) wts[tid] = (float)counts64[ord[tid]];
  __syncthreads();
  if (tid < KC) {                                // stable argsort(-wts)
    float wi = wts[tid]; int r = 0;
    for (int s = 0; s < KC; ++s) {
      float wsv = wts[s];
      r += (wsv > wi) || (wsv == wi && s < tid);
    }
    ord2[r] = tid;
  }
  __syncthreads();
  if (tid < KC) {
    int j = ord[tid];
    orderws[tid] = j;
    out_w[tid] = (float)counts64[j];
    out_ts[tid] = rintf(times[j]);
    Nout[tid] = Ns[tid];
  }
  if (tid < NSEL) sel[tid] = ord[ord2[tid]];
  if (tid < KC) {                                // member lists (last-live membership)
    int c = 0;
#pragma unroll
    for (int w = 0; w < 4; ++w) {
      unsigned long long mm = membw[tid][w];
      while (mm) {
        int b = __builtin_ctzll(mm);
        mlist[tid * 256 + (c++)] = w * 64 + b;
        mm &= mm - 1;
      }
    }
    mcount[tid] = c;
  }
  __syncthreads();

  // ---- distidx: 30 argmins; wave w handles sels {w, w+16} ----
  {
    int wid = tid >> 6;
    for (int s = wid; s < NSEL; s += 16) {
      int j = sel[s];
      double qn = qi[j][0], iv = qi[j][1];
      unsigned long long key = ~0ULL;
#pragma unroll
      for (int q = 0; q < 4; ++q) {
        int p = lane + 64 * q;
        double v = giiL[p] + qn - 2.0 * S[j][p] * iv;
        float dd = sqrtf(fmaxf((float)v, 0.0f));
        unsigned long long k = (((unsigned long long)__float_as_uint(dd)) << 32) | (unsigned)p;
        if (k < key) key = k;
      }
#pragma unroll
      for (int o = 32; o > 0; o >>= 1) {
        unsigned long long other = __shfl_xor(key, o, 64);
        if (other < key) key = other;
      }
      if (lane == 0) { int bi = (int)(key & 0xffffffffULL); idxws[s] = bi; out_idx[s] = (float)bi; }
    }
  }
}

// ---------------- Stage E fused: gather_spa + write_tem ---------------------
__global__ void tail_kernel(const float* __restrict__ x, const int* __restrict__ idxws,
                            const __hip_bfloat16* __restrict__ HB,
                            const __hip_bfloat16* __restrict__ MB,
                            const int* __restrict__ orderws,
                            const int* __restrict__ mcount, const int* __restrict__ mlist,
                            const int* __restrict__ N,
                            float* __restrict__ out_cat, float* __restrict__ out_tem) {
  int bid = blockIdx.x;
  if (bid < 8820) {
    int pos = bid * 256 + threadIdx.x;           // 30*75264 float4s
    int s = pos / 75264;
    int o = pos - s * 75264;
    ((float4*)out_cat)[pos] = ((const float4*)x)[(size_t)idxws[s] * 75264 + o];
  } else {
    int b2 = bid - 8820;
    int r = b2 / 37, g = b2 - r * 37;
    int col8 = g * 256 + threadIdx.x;            // 9408 groups of 8 elements
    if (col8 >= 9408) return;
    int j = orderws[r];
    int cntm = mcount[j];
    float n = (float)N[j];
    float acc[8];
#pragma unroll
    for (int k = 0; k < 8; ++k) acc[k] = 0.f;
    for (int m = 0; m < cntm; ++m) {
      int p = mlist[j * 256 + m];
      u16x8 hv = *(const u16x8*)((const unsigned short*)HB + (size_t)p * GK + (size_t)col8 * 8);
      u16x8 mv = *(const u16x8*)((const unsigned short*)MB + (size_t)p * GK + (size_t)col8 * 8);
#pragma unroll
      for (int k = 0; k < 8; ++k) acc[k] += b2f(hv[k]) + b2f(mv[k]);
    }
    float4 o0 = make_float4(acc[0] / n, acc[1] / n, acc[2] / n, acc[3] / n);
    float4 o1 = make_float4(acc[4] / n, acc[5] / n, acc[6] / n, acc[7] / n);
    float4* dst = (float4*)out_tem + (size_t)r * 18816 + (size_t)col8 * 2;
    dst[0] = o0;
    dst[1] = o1;
  }
}

extern "C" void kernel_launch(void* const* d_in, const int* in_sizes, int n_in,
                              void* d_out, int out_size, void* d_ws, size_t ws_size,
                              hipStream_t stream) {
  const float* x = (const float*)d_in[0];
  char* ws = (char*)d_ws;
  size_t off = 0;
  __hip_bfloat16* HB = (__hip_bfloat16*)(ws + off); off += (size_t)19267584 * 2;  // 38.5 MB
  __hip_bfloat16* MB = (__hip_bfloat16*)(ws + off); off += (size_t)19267584 * 2;  // 38.5 MB
  double* G    = (double*)(ws + off);    off += (size_t)65536 * 8;
  int* orderws = (int*)(ws + off);       off += 256;
  int* idxws   = (int*)(ws + off);       off += 256;
  int* mcount  = (int*)(ws + off);       off += 256;
  int* Nws     = (int*)(ws + off);       off += 256;
  int* mlist   = (int*)(ws + off);       off += (size_t)KC * 256 * 4;

  float* out = (float*)d_out;
  float* gpart = out;  // NCH*256KB = 51.4 MB scratch inside cat_x region; overwritten later

  const size_t o_cat = 0;
  const size_t o_tem = 9031680;
  const size_t o_idx = 13547520;
  const size_t o_ts  = o_idx + 30;
  const size_t o_w   = o_ts + 60;

  pool_kernel<<<75264, 256, 0, stream>>>(x, HB, MB);
  gram_mfma<<<NCH, 512, 0, stream>>>((const unsigned short*)HB, (const unsigned short*)MB, gpart);
  reduceG<<<256, 256, 0, stream>>>(gpart, G);
  kmeans_all<<<1, 1024, 0, stream>>>(G, orderws, idxws, mcount, mlist, Nws,
                                     out + o_idx, out + o_ts, out + o_w);
  tail_kernel<<<8820 + KC * 37, 256, 0, stream>>>(x, idxws, HB, MB, orderws, mcount, mlist,
                                                  Nws, out + o_cat, out + o_tem);
}